// Round 1
// baseline (925.405 us; speedup 1.0000x reference)
//
#include <hip/hip_runtime.h>
#include <hip/hip_bf16.h>
#include <math.h>

#define NRES 768
#define C1 384
#define C2 128
#define NH 12

// ws float offsets
#define OFF_QS   0
#define OFF_KS   147456
#define OFF_VS   294912
#define OFF_QPT  442368
#define OFF_KPT  552960
#define OFF_VPT  663552
#define OFF_FA   884736
// fa: 768 * 2112

__device__ __forceinline__ float dot4(float4 a, float4 b) {
    return fmaf(a.x, b.x, fmaf(a.y, b.y, fmaf(a.z, b.z, a.w * b.w)));
}

static constexpr float SCALAR_W = 0.14433756729740643f; // sqrt(1/48)
static constexpr float POINT_W  = 0.13608276348795434f; // sqrt(1/54)
static constexpr float W2D_W    = 0.57735026918962576f; // sqrt(1/3)

// ---------------------------------------------------------------------------
// K1: input projections + rotation/translation of point projections.
// 96 blocks x 256 threads, 8 residues per block (weights stay L2-resident).
// ---------------------------------------------------------------------------
__global__ __launch_bounds__(256) void k1_proj(
    const float* __restrict__ in1d,
    const float* __restrict__ rot, const float* __restrict__ trans,
    const float* __restrict__ w_qs, const float* __restrict__ b_qs,
    const float* __restrict__ w_kvs, const float* __restrict__ b_kvs,
    const float* __restrict__ w_qp, const float* __restrict__ b_qp,
    const float* __restrict__ w_kvp, const float* __restrict__ b_kvp,
    float* __restrict__ ws)
{
    __shared__ __align__(16) float inS[8][C1];
    __shared__ __align__(16) float rawS[8][1156];   // 1152 padded to 1156 (bank spread)
    __shared__ float rotS[8][9];
    __shared__ float trS[8][3];
    const int t = threadIdx.x;
    const int i0 = blockIdx.x * 8;

    for (int f = t; f < 8 * C1 / 4; f += 256) {
        int pos = f * 4; int r = pos / C1; int c = pos % C1;
        *(float4*)&inS[r][c] = *(const float4*)&in1d[(size_t)(i0 + r) * C1 + c];
    }
    if (t < 72) rotS[t / 9][t % 9] = rot[i0 * 9 + t];
    if (t < 24) trS[t / 3][t % 3] = trans[i0 * 3 + t];
    __syncthreads();

    for (int oi = 0; oi < 5; ++oi) {
        int o = t + 256 * oi;
        if (o >= 1152) break;
        const float* wrow; float bias;
        if (o < 192)      { wrow = w_qs  + (size_t)o * C1;          bias = b_qs[o]; }
        else if (o < 576) { wrow = w_kvs + (size_t)(o - 192) * C1;  bias = b_kvs[o - 192]; }
        else if (o < 720) { wrow = w_qp  + (size_t)(o - 576) * C1;  bias = b_qp[o - 576]; }
        else              { wrow = w_kvp + (size_t)(o - 720) * C1;  bias = b_kvp[o - 720]; }
        float acc[8];
        #pragma unroll
        for (int r = 0; r < 8; ++r) acc[r] = 0.f;
        for (int c4 = 0; c4 < C1 / 4; ++c4) {
            float4 w4 = *(const float4*)&wrow[c4 * 4];
            #pragma unroll
            for (int r = 0; r < 8; ++r) {
                float4 v4 = *(const float4*)&inS[r][c4 * 4];
                acc[r] += dot4(w4, v4);
            }
        }
        #pragma unroll
        for (int r = 0; r < 8; ++r) rawS[r][o] = acc[r] + bias;
    }
    __syncthreads();

    float* qs  = ws + OFF_QS;  float* ks  = ws + OFF_KS;  float* vs  = ws + OFF_VS;
    float* qpt = ws + OFF_QPT; float* kpt = ws + OFF_KPT; float* vpt = ws + OFF_VPT;

    // scalars
    for (int it = t; it < 8 * 576; it += 256) {
        int r = it / 576, o = it % 576;
        int n = i0 + r;
        float v = rawS[r][o];
        if (o < 192) {
            qs[n * 192 + o] = v * SCALAR_W;
        } else {
            int idx = o - 192; int h = idx >> 5; int d = idx & 31;
            if (d < 16) ks[n * 192 + h * 16 + d] = v;
            else        vs[n * 192 + h * 16 + (d - 16)] = v;
        }
    }
    // points: apply global frame (rot @ p + trans)
    for (int it = t; it < 8 * 192; it += 256) {
        int r = it / 192, m = it % 192;
        int n = i0 + r;
        float x0, x1, x2;
        if (m < 48) {
            x0 = rawS[r][576 + m]; x1 = rawS[r][576 + 48 + m]; x2 = rawS[r][576 + 96 + m];
        } else {
            int mm = m - 48;
            x0 = rawS[r][720 + mm]; x1 = rawS[r][720 + 144 + mm]; x2 = rawS[r][720 + 288 + mm];
        }
        float g[3];
        #pragma unroll
        for (int ii = 0; ii < 3; ++ii)
            g[ii] = rotS[r][ii * 3 + 0] * x0 + rotS[r][ii * 3 + 1] * x1 + rotS[r][ii * 3 + 2] * x2 + trS[r][ii];
        if (m < 48) {
            #pragma unroll
            for (int ii = 0; ii < 3; ++ii) qpt[n * 144 + 3 * m + ii] = g[ii];
        } else {
            int mm = m - 48; int h = mm / 12, pp = mm % 12;
            if (pp < 4) {
                #pragma unroll
                for (int ii = 0; ii < 3; ++ii) kpt[n * 144 + h * 12 + pp * 3 + ii] = g[ii];
            } else {
                #pragma unroll
                for (int ii = 0; ii < 3; ++ii) vpt[n * 288 + h * 24 + (pp - 4) * 3 + ii] = g[ii];
            }
        }
    }
}

// ---------------------------------------------------------------------------
// K2: per-row fused attention. One block per query residue i.
// ---------------------------------------------------------------------------
__global__ __launch_bounds__(256) void k2_attn(
    const float* __restrict__ in2d,
    const float* __restrict__ mask,
    const float* __restrict__ rot, const float* __restrict__ trans,
    const float* __restrict__ tpw,
    const float* __restrict__ w2d, const float* __restrict__ b2d,
    float* __restrict__ ws)
{
    __shared__ __align__(16) float L[NH][NRES];
    __shared__ __align__(16) float qsS[192];
    __shared__ __align__(16) float qptS[144];
    __shared__ float qnS[NH];
    __shared__ float phS[NH];
    __shared__ float bbS[NH];
    __shared__ float rpgS[288];
    const int t = threadIdx.x;
    const int i = blockIdx.x;

    const float* qs  = ws + OFF_QS;  const float* ks  = ws + OFF_KS;  const float* vs = ws + OFF_VS;
    const float* qpt = ws + OFF_QPT; const float* kpt = ws + OFF_KPT; const float* vpt = ws + OFF_VPT;

    if (t < 48) *(float4*)&qsS[t * 4] = *(const float4*)&qs[(size_t)i * 192 + t * 4];
    if (t >= 64 && t < 100) { int u = t - 64; *(float4*)&qptS[u * 4] = *(const float4*)&qpt[(size_t)i * 144 + u * 4]; }
    __syncthreads();
    if (t < NH) {
        float s = 0.f;
        #pragma unroll
        for (int e = 0; e < 12; ++e) { float x = qptS[t * 12 + e]; s += x * x; }
        qnS[t] = s;
        float tw = tpw[t];
        float sp = logf(1.f + __expf(tw));       // softplus
        phS[t] = -0.5f * sp * POINT_W;
        bbS[t] = W2D_W * b2d[t];
    }
    __syncthreads();
    const float mi = mask[i];

    // ---- Phase A: logits ----
    for (int jj = t; jj < NRES; jj += 256) {
        float acc[NH];
        #pragma unroll
        for (int h = 0; h < NH; ++h) acc[h] = 0.f;
        const float* row = in2d + ((size_t)i * NRES + jj) * C2;
        for (int c4 = 0; c4 < C2 / 4; ++c4) {
            float4 v4 = *(const float4*)&row[c4 * 4];
            #pragma unroll
            for (int h = 0; h < NH; ++h) {
                float4 w4 = *(const float4*)(w2d + h * C2 + c4 * 4);  // wave-uniform -> s_load
                acc[h] += dot4(v4, w4);
            }
        }
        const float msub = -100000.0f * (1.0f - mi * mask[jj]);
        const float* ksr  = ks  + (size_t)jj * 192;
        const float* kptr = kpt + (size_t)jj * 144;
        #pragma unroll
        for (int h = 0; h < NH; ++h) {
            float sq = 0.f;
            #pragma unroll
            for (int d4 = 0; d4 < 4; ++d4) {
                float4 q4 = *(const float4*)&qsS[h * 16 + d4 * 4];
                float4 k4 = *(const float4*)&ksr[h * 16 + d4 * 4];
                sq += dot4(q4, k4);
            }
            float qk = 0.f, kk = 0.f;
            #pragma unroll
            for (int e4 = 0; e4 < 3; ++e4) {
                float4 qp4 = *(const float4*)&qptS[h * 12 + e4 * 4];
                float4 kp4 = *(const float4*)&kptr[h * 12 + e4 * 4];
                qk += dot4(qp4, kp4);
                kk += dot4(kp4, kp4);
            }
            L[h][jj] = sq + phS[h] * (qnS[h] + kk - 2.f * qk) + W2D_W * acc[h] + bbS[h] + msub;
        }
    }
    __syncthreads();

    // ---- softmax: wave w handles heads w, w+4, w+8 ----
    {
        int wv = t >> 6; int lane = t & 63;
        for (int h = wv; h < NH; h += 4) {
            float m = -1e30f;
            for (int j = lane; j < NRES; j += 64) m = fmaxf(m, L[h][j]);
            #pragma unroll
            for (int o = 32; o > 0; o >>= 1) m = fmaxf(m, __shfl_xor(m, o));
            float s = 0.f;
            for (int j = lane; j < NRES; j += 64) {
                float e = __expf(L[h][j] - m);
                L[h][j] = e; s += e;
            }
            #pragma unroll
            for (int o = 32; o > 0; o >>= 1) s += __shfl_xor(s, o);
            float rinv = 1.0f / s;
            for (int j = lane; j < NRES; j += 64) L[h][j] *= rinv;
        }
    }
    __syncthreads();

    float* fa = ws + OFF_FA + (size_t)i * 2112;

    // ---- Phase B: r2d = attn @ inputs_2d, 192 threads, (2h x 4c) per thread ----
    if (t < 192) {
        int hg = t >> 5;           // 0..5
        int cg = t & 31;           // 0..31
        int h0 = hg * 2, h1 = h0 + 1;
        int c0 = cg * 4;
        float a0[4] = {0.f, 0.f, 0.f, 0.f};
        float a1[4] = {0.f, 0.f, 0.f, 0.f};
        const float* base = in2d + (size_t)i * NRES * C2 + c0;
        for (int j0 = 0; j0 < NRES; j0 += 4) {
            float4 A0 = *(const float4*)&L[h0][j0];
            float4 A1 = *(const float4*)&L[h1][j0];
            float w0[4] = {A0.x, A0.y, A0.z, A0.w};
            float w1[4] = {A1.x, A1.y, A1.z, A1.w};
            #pragma unroll
            for (int k = 0; k < 4; ++k) {
                float4 v4 = *(const float4*)&base[(size_t)(j0 + k) * C2];
                a0[0] = fmaf(w0[k], v4.x, a0[0]); a0[1] = fmaf(w0[k], v4.y, a0[1]);
                a0[2] = fmaf(w0[k], v4.z, a0[2]); a0[3] = fmaf(w0[k], v4.w, a0[3]);
                a1[0] = fmaf(w1[k], v4.x, a1[0]); a1[1] = fmaf(w1[k], v4.y, a1[1]);
                a1[2] = fmaf(w1[k], v4.z, a1[2]); a1[3] = fmaf(w1[k], v4.w, a1[3]);
            }
        }
        *(float4*)&fa[576 + h0 * 128 + c0] = make_float4(a0[0], a0[1], a0[2], a0[3]);
        *(float4*)&fa[576 + h1 * 128 + c0] = make_float4(a1[0], a1[1], a1[2], a1[3]);
    }

    // ---- Phase B2: result_scalar (192 outs) + rpg (288 outs) ----
    for (int o = t; o < 480; o += 256) {
        if (o < 192) {
            int h = o >> 4;
            const float* vcol = vs + (o & 15) + (o >> 4) * 16;
            float s = 0.f;
            for (int j0 = 0; j0 < NRES; j0 += 4) {
                float4 A = *(const float4*)&L[h][j0];
                s = fmaf(A.x, vcol[(size_t)(j0 + 0) * 192], s);
                s = fmaf(A.y, vcol[(size_t)(j0 + 1) * 192], s);
                s = fmaf(A.z, vcol[(size_t)(j0 + 2) * 192], s);
                s = fmaf(A.w, vcol[(size_t)(j0 + 3) * 192], s);
            }
            fa[o] = s;
        } else {
            int q = o - 192;
            int h = q / 24;
            const float* vcol = vpt + q;   // q = h*24 + p*3 + c, matches vpt row layout
            float s = 0.f;
            for (int j0 = 0; j0 < NRES; j0 += 4) {
                float4 A = *(const float4*)&L[h][j0];
                s = fmaf(A.x, vcol[(size_t)(j0 + 0) * 288], s);
                s = fmaf(A.y, vcol[(size_t)(j0 + 1) * 288], s);
                s = fmaf(A.z, vcol[(size_t)(j0 + 2) * 288], s);
                s = fmaf(A.w, vcol[(size_t)(j0 + 3) * 288], s);
            }
            rpgS[q] = s;
        }
    }
    __syncthreads();

    // ---- epilogue: local frame transform + dist ----
    if (t < 96) {
        int h = t >> 3, p = t & 7;
        float rv[3];
        #pragma unroll
        for (int c = 0; c < 3; ++c) rv[c] = rpgS[h * 24 + p * 3 + c] - trans[i * 3 + c];
        float l0 = rot[i * 9 + 0] * rv[0] + rot[i * 9 + 3] * rv[1] + rot[i * 9 + 6] * rv[2];
        float l1 = rot[i * 9 + 1] * rv[0] + rot[i * 9 + 4] * rv[1] + rot[i * 9 + 7] * rv[2];
        float l2 = rot[i * 9 + 2] * rv[0] + rot[i * 9 + 5] * rv[1] + rot[i * 9 + 8] * rv[2];
        float dd = sqrtf(1e-8f + l0 * l0 + l1 * l1 + l2 * l2);
        fa[192 + t] = l0;
        fa[288 + t] = l1;
        fa[384 + t] = l2;
        fa[480 + t] = dd;
    }
}

// ---------------------------------------------------------------------------
// K3: out = final_act @ w_out.T + b_out.  32x32 tiles, 2x2 micro-tile.
// ---------------------------------------------------------------------------
__global__ __launch_bounds__(256) void k3_out(
    const float* __restrict__ w_out, const float* __restrict__ b_out,
    const float* __restrict__ ws, float* __restrict__ out)
{
    __shared__ __align__(16) float ASt[32][34];
    __shared__ __align__(16) float WSt[32][34];
    const int t = threadIdx.x;
    const int i0 = blockIdx.x * 32;   // 24 tiles
    const int o0 = blockIdx.y * 32;   // 12 tiles
    const float* fa = ws + OFF_FA;
    int tx = t & 15, ty = t >> 4;
    float acc00 = 0.f, acc01 = 0.f, acc10 = 0.f, acc11 = 0.f;
    int r = t >> 3, kq = (t & 7) * 4;

    for (int k0 = 0; k0 < 2112; k0 += 32) {
        __syncthreads();
        {
            float4 a4 = *(const float4*)&fa[(size_t)(i0 + r) * 2112 + k0 + kq];
            ASt[kq + 0][r] = a4.x; ASt[kq + 1][r] = a4.y; ASt[kq + 2][r] = a4.z; ASt[kq + 3][r] = a4.w;
            float4 w4 = *(const float4*)&w_out[(size_t)(o0 + r) * 2112 + k0 + kq];
            WSt[kq + 0][r] = w4.x; WSt[kq + 1][r] = w4.y; WSt[kq + 2][r] = w4.z; WSt[kq + 3][r] = w4.w;
        }
        __syncthreads();
        #pragma unroll
        for (int k = 0; k < 32; ++k) {
            float2 av = *(const float2*)&ASt[k][ty * 2];
            float2 wv = *(const float2*)&WSt[k][tx * 2];
            acc00 = fmaf(av.x, wv.x, acc00);
            acc01 = fmaf(av.x, wv.y, acc01);
            acc10 = fmaf(av.y, wv.x, acc10);
            acc11 = fmaf(av.y, wv.y, acc11);
        }
    }
    int oi = i0 + ty * 2, oo = o0 + tx * 2;
    out[(size_t)oi * 384 + oo]           = acc00 + b_out[oo];
    out[(size_t)oi * 384 + oo + 1]       = acc01 + b_out[oo + 1];
    out[(size_t)(oi + 1) * 384 + oo]     = acc10 + b_out[oo];
    out[(size_t)(oi + 1) * 384 + oo + 1] = acc11 + b_out[oo + 1];
}

extern "C" void kernel_launch(void* const* d_in, const int* in_sizes, int n_in,
                              void* d_out, int out_size, void* d_ws, size_t ws_size,
                              hipStream_t stream) {
    const float* in1d  = (const float*)d_in[0];
    const float* in2d  = (const float*)d_in[1];
    const float* mask  = (const float*)d_in[2];
    const float* rot   = (const float*)d_in[3];
    const float* trans = (const float*)d_in[4];
    const float* w_qs  = (const float*)d_in[5];
    const float* b_qs  = (const float*)d_in[6];
    const float* w_kvs = (const float*)d_in[7];
    const float* b_kvs = (const float*)d_in[8];
    const float* w_qp  = (const float*)d_in[9];
    const float* b_qp  = (const float*)d_in[10];
    const float* w_kvp = (const float*)d_in[11];
    const float* b_kvp = (const float*)d_in[12];
    const float* tpw   = (const float*)d_in[13];
    const float* w2d   = (const float*)d_in[14];
    const float* b2d   = (const float*)d_in[15];
    const float* w_out = (const float*)d_in[16];
    const float* b_out = (const float*)d_in[17];
    float* ws  = (float*)d_ws;
    float* out = (float*)d_out;

    hipLaunchKernelGGL(k1_proj, dim3(96), dim3(256), 0, stream,
                       in1d, rot, trans, w_qs, b_qs, w_kvs, b_kvs, w_qp, b_qp, w_kvp, b_kvp, ws);
    hipLaunchKernelGGL(k2_attn, dim3(768), dim3(256), 0, stream,
                       in2d, mask, rot, trans, tpw, w2d, b2d, ws);
    hipLaunchKernelGGL(k3_out, dim3(24, 12), dim3(256), 0, stream,
                       w_out, b_out, ws, out);
}

// Round 2
// 702.298 us; speedup vs baseline: 1.3177x; 1.3177x over previous
//
#include <hip/hip_runtime.h>
#include <hip/hip_bf16.h>
#include <math.h>

#define NRES 768
#define C1 384
#define C2 128
#define NH 12

// ws float offsets
#define OFF_QS   0          // 768*192
#define OFF_KS   147456
#define OFF_VS   294912
#define OFF_QPT  442368     // 768*144
#define OFF_KPT  552960
#define OFF_VPT  663552     // 768*288
#define OFF_FA   884736     // 768*2112
#define OFF_RAW  OFF_FA     // raw projections aliased into fa region (consumed by k1b before k2 writes fa)

__device__ __forceinline__ float dot4(float4 a, float4 b) {
    return fmaf(a.x, b.x, fmaf(a.y, b.y, fmaf(a.z, b.z, a.w * b.w)));
}

static constexpr float SCALAR_W = 0.14433756729740643f; // sqrt(1/48)
static constexpr float POINT_W  = 0.13608276348795434f; // sqrt(1/54)
static constexpr float W2D_W    = 0.57735026918962576f; // sqrt(1/3)

__device__ __forceinline__ void wsel(int o,
    const float* w_qs, const float* b_qs, const float* w_kvs, const float* b_kvs,
    const float* w_qp, const float* b_qp, const float* w_kvp, const float* b_kvp,
    const float** row, float* bias)
{
    if (o < 192)      { *row = w_qs  + (size_t)o * C1;         *bias = b_qs[o]; }
    else if (o < 576) { *row = w_kvs + (size_t)(o - 192) * C1; *bias = b_kvs[o - 192]; }
    else if (o < 720) { *row = w_qp  + (size_t)(o - 576) * C1; *bias = b_qp[o - 576]; }
    else              { *row = w_kvp + (size_t)(o - 720) * C1; *bias = b_kvp[o - 720]; }
}

// ---------------------------------------------------------------------------
// K1: raw = in1d @ W_all.T + b_all  (768 x 1152, K=384), tiled GEMM.
// grid (12, 18), 64x64 tile, 4x4 micro-tile per thread.
// ---------------------------------------------------------------------------
__global__ __launch_bounds__(256) void k1_gemm(
    const float* __restrict__ in1d,
    const float* __restrict__ w_qs, const float* __restrict__ b_qs,
    const float* __restrict__ w_kvs, const float* __restrict__ b_kvs,
    const float* __restrict__ w_qp, const float* __restrict__ b_qp,
    const float* __restrict__ w_kvp, const float* __restrict__ b_kvp,
    float* __restrict__ ws)
{
    __shared__ __align__(16) float ASt[32][68];
    __shared__ __align__(16) float WSt[32][68];
    const int t = threadIdx.x;
    const int n0 = blockIdx.x * 64;
    const int o0 = blockIdx.y * 64;
    const int tx = t & 15, ty = t >> 4;
    float acc[4][4];
    #pragma unroll
    for (int r = 0; r < 4; ++r)
        #pragma unroll
        for (int c = 0; c < 4; ++c) acc[r][c] = 0.f;

    for (int k0 = 0; k0 < C1; k0 += 32) {
        __syncthreads();
        #pragma unroll
        for (int s = 0; s < 2; ++s) {
            int q = t + 256 * s;
            int row = q >> 3, kq = (q & 7) * 4;
            float4 a4 = *(const float4*)&in1d[(size_t)(n0 + row) * C1 + k0 + kq];
            ASt[kq + 0][row] = a4.x; ASt[kq + 1][row] = a4.y;
            ASt[kq + 2][row] = a4.z; ASt[kq + 3][row] = a4.w;
            const float* wr; float bb;
            wsel(o0 + row, w_qs, b_qs, w_kvs, b_kvs, w_qp, b_qp, w_kvp, b_kvp, &wr, &bb);
            float4 w4 = *(const float4*)&wr[k0 + kq];
            WSt[kq + 0][row] = w4.x; WSt[kq + 1][row] = w4.y;
            WSt[kq + 2][row] = w4.z; WSt[kq + 3][row] = w4.w;
        }
        __syncthreads();
        #pragma unroll
        for (int k = 0; k < 32; ++k) {
            float4 a4 = *(const float4*)&ASt[k][ty * 4];
            float4 w4 = *(const float4*)&WSt[k][tx * 4];
            float av[4] = {a4.x, a4.y, a4.z, a4.w};
            float wv[4] = {w4.x, w4.y, w4.z, w4.w};
            #pragma unroll
            for (int r = 0; r < 4; ++r)
                #pragma unroll
                for (int c = 0; c < 4; ++c)
                    acc[r][c] = fmaf(av[r], wv[c], acc[r][c]);
        }
    }
    float bias[4];
    #pragma unroll
    for (int c = 0; c < 4; ++c) {
        const float* dummy;
        wsel(o0 + tx * 4 + c, w_qs, b_qs, w_kvs, b_kvs, w_qp, b_qp, w_kvp, b_kvp, &dummy, &bias[c]);
    }
    float* raw = ws + OFF_RAW;
    #pragma unroll
    for (int r = 0; r < 4; ++r) {
        int n = n0 + ty * 4 + r;
        *(float4*)&raw[(size_t)n * 1152 + o0 + tx * 4] =
            make_float4(acc[r][0] + bias[0], acc[r][1] + bias[1],
                        acc[r][2] + bias[2], acc[r][3] + bias[3]);
    }
}

// ---------------------------------------------------------------------------
// K1b: scatter raw projections into qs/ks/vs and apply global frame to points.
// grid 768 (one residue per block).
// ---------------------------------------------------------------------------
__global__ __launch_bounds__(256) void k1b_scatter(
    const float* __restrict__ rot, const float* __restrict__ trans,
    float* __restrict__ ws)
{
    __shared__ __align__(16) float rawS[1152];
    const int t = threadIdx.x;
    const int i = blockIdx.x;
    const float* raw = ws + OFF_RAW + (size_t)i * 1152;
    for (int q = t; q < 288; q += 256) *(float4*)&rawS[q * 4] = *(const float4*)&raw[q * 4];
    __syncthreads();
    float* qs  = ws + OFF_QS;  float* ks  = ws + OFF_KS;  float* vs  = ws + OFF_VS;
    float* qpt = ws + OFF_QPT; float* kpt = ws + OFF_KPT; float* vpt = ws + OFF_VPT;

    for (int o = t; o < 576; o += 256) {
        float v = rawS[o];
        if (o < 192) {
            qs[(size_t)i * 192 + o] = v * SCALAR_W;
        } else {
            int idx = o - 192, h = idx >> 5, d = idx & 31;
            if (d < 16) ks[(size_t)i * 192 + h * 16 + d] = v;
            else        vs[(size_t)i * 192 + h * 16 + (d - 16)] = v;
        }
    }
    if (t < 192) {
        int m = t;
        float x0, x1, x2;
        if (m < 48) { x0 = rawS[576 + m]; x1 = rawS[624 + m]; x2 = rawS[672 + m]; }
        else { int mm = m - 48; x0 = rawS[720 + mm]; x1 = rawS[864 + mm]; x2 = rawS[1008 + mm]; }
        float g[3];
        #pragma unroll
        for (int ii = 0; ii < 3; ++ii)
            g[ii] = rot[i * 9 + ii * 3 + 0] * x0 + rot[i * 9 + ii * 3 + 1] * x1 +
                    rot[i * 9 + ii * 3 + 2] * x2 + trans[i * 3 + ii];
        if (m < 48) {
            #pragma unroll
            for (int ii = 0; ii < 3; ++ii) qpt[(size_t)i * 144 + 3 * m + ii] = g[ii];
        } else {
            int mm = m - 48, h = mm / 12, pp = mm % 12;
            if (pp < 4) {
                #pragma unroll
                for (int ii = 0; ii < 3; ++ii) kpt[(size_t)i * 144 + h * 12 + pp * 3 + ii] = g[ii];
            } else {
                #pragma unroll
                for (int ii = 0; ii < 3; ++ii) vpt[(size_t)i * 288 + h * 24 + (pp - 4) * 3 + ii] = g[ii];
            }
        }
    }
}

// ---------------------------------------------------------------------------
// K2: fused single-pass online-softmax IPA row kernel. One block per i.
// ---------------------------------------------------------------------------
#define TJ 256
__global__ __launch_bounds__(256) void k2_attn(
    const float* __restrict__ in2d,
    const float* __restrict__ mask,
    const float* __restrict__ rot, const float* __restrict__ trans,
    const float* __restrict__ tpw,
    const float* __restrict__ w2d, const float* __restrict__ b2d,
    float* __restrict__ ws)
{
    __shared__ __align__(16) float P[NH][264];       // logits -> exp weights, stride 264 (16B-aligned rows)
    __shared__ __align__(16) float tileS[64][128];   // in2d subtile
    __shared__ __align__(16) float qsS[192];
    __shared__ __align__(16) float qptS[144];
    __shared__ float qnS[NH], phS[NH], bbS[NH], mS[NH], lS[NH], aS[NH];
    __shared__ float rpgS[288];
    const int t = threadIdx.x;
    const int i = blockIdx.x;

    const float* qs  = ws + OFF_QS;  const float* ks  = ws + OFF_KS;  const float* vs = ws + OFF_VS;
    const float* qpt = ws + OFF_QPT; const float* kpt = ws + OFF_KPT; const float* vpt = ws + OFF_VPT;

    if (t < 48) *(float4*)&qsS[t * 4] = *(const float4*)&qs[(size_t)i * 192 + t * 4];
    else if (t >= 64 && t < 100) { int u = t - 64; *(float4*)&qptS[u * 4] = *(const float4*)&qpt[(size_t)i * 144 + u * 4]; }
    __syncthreads();
    if (t < NH) {
        float s = 0.f;
        #pragma unroll
        for (int e = 0; e < 12; ++e) { float x = qptS[t * 12 + e]; s += x * x; }
        qnS[t] = s;
        phS[t] = -0.5f * POINT_W * logf(1.f + __expf(tpw[t]));
        bbS[t] = W2D_W * b2d[t];
        mS[t] = -1e30f;
        lS[t] = 0.f;
    }
    __syncthreads();
    const float mi = mask[i];

    // persistent accumulators (unnormalized, rescaled by alpha each tile)
    float ra[4] = {0.f, 0.f, 0.f, 0.f};
    float rb[4] = {0.f, 0.f, 0.f, 0.f};
    const bool isR2 = (t < 192);
    int h0 = 0, h1 = 0, c4 = 0, o0 = 0, vh = 0;
    const float* vbase = nullptr; int vstride = 0; bool vact = false;
    if (isR2) { h0 = (t >> 5) * 2; h1 = h0 + 1; c4 = t & 31; }
    else {
        int u = t - 192; o0 = u * 8; vact = (u < 60);
        if (vact) {
            if (o0 < 192) { vh = o0 >> 4; vbase = vs + o0; vstride = 192; }
            else { int q0 = o0 - 192; vh = q0 / 24; vbase = vpt + q0; vstride = 288; }
        }
    }

    for (int tile = 0; tile < 3; ++tile) {
        const int j0 = tile * TJ;
        __syncthreads();   // P reuse safety across tiles
        // ---- phase A: logits for j = j0 + t ----
        {
            const int j = j0 + t;
            float acc[NH];
            #pragma unroll
            for (int h = 0; h < NH; ++h) acc[h] = 0.f;
            const float* row = in2d + ((size_t)i * NRES + j) * C2;
            #pragma unroll 8
            for (int cc = 0; cc < 32; ++cc) {
                float4 v4 = *(const float4*)&row[cc * 4];
                #pragma unroll
                for (int h = 0; h < NH; ++h) {
                    float4 w4 = *(const float4*)&w2d[h * C2 + cc * 4];  // wave-uniform -> s_load
                    acc[h] += dot4(v4, w4);
                }
            }
            const float msub = -100000.0f * (1.0f - mi * mask[j]);
            const float* ksr  = ks  + (size_t)j * 192;
            const float* kptr = kpt + (size_t)j * 144;
            #pragma unroll
            for (int h = 0; h < NH; ++h) {
                float sq = 0.f;
                #pragma unroll
                for (int d4 = 0; d4 < 4; ++d4) {
                    float4 q4 = *(const float4*)&qsS[h * 16 + d4 * 4];
                    float4 k4 = *(const float4*)&ksr[h * 16 + d4 * 4];
                    sq += dot4(q4, k4);
                }
                float qk = 0.f, kk = 0.f;
                #pragma unroll
                for (int e4 = 0; e4 < 3; ++e4) {
                    float4 qp4 = *(const float4*)&qptS[h * 12 + e4 * 4];
                    float4 kp4 = *(const float4*)&kptr[h * 12 + e4 * 4];
                    qk += dot4(qp4, kp4);
                    kk += dot4(kp4, kp4);
                }
                P[h][t] = sq + phS[h] * (qnS[h] + kk - 2.f * qk) + W2D_W * acc[h] + bbS[h] + msub;
            }
        }
        __syncthreads();
        // ---- online softmax update over this tile: wave wv handles 3 heads ----
        {
            int wv = t >> 6, lane = t & 63;
            for (int h = wv * 3; h < wv * 3 + 3; ++h) {
                float v0 = P[h][lane], v1 = P[h][lane + 64], v2 = P[h][lane + 128], v3 = P[h][lane + 192];
                float mt = fmaxf(fmaxf(v0, v1), fmaxf(v2, v3));
                #pragma unroll
                for (int off = 32; off > 0; off >>= 1) mt = fmaxf(mt, __shfl_xor(mt, off));
                float mold = mS[h];
                float mnew = fmaxf(mold, mt);
                float e0 = __expf(v0 - mnew), e1 = __expf(v1 - mnew);
                float e2 = __expf(v2 - mnew), e3 = __expf(v3 - mnew);
                P[h][lane] = e0; P[h][lane + 64] = e1; P[h][lane + 128] = e2; P[h][lane + 192] = e3;
                float s = e0 + e1 + e2 + e3;
                #pragma unroll
                for (int off = 32; off > 0; off >>= 1) s += __shfl_xor(s, off);
                if (lane == 0) {
                    float a = __expf(mold - mnew);
                    aS[h] = a;
                    lS[h] = lS[h] * a + s;
                    mS[h] = mnew;
                }
            }
        }
        __syncthreads();
        // ---- rescale persistent accumulators ----
        if (isR2) {
            float a0 = aS[h0], a1 = aS[h1];
            #pragma unroll
            for (int k = 0; k < 4; ++k) { ra[k] *= a0; rb[k] *= a1; }
        } else if (vact) {
            float a = aS[vh];
            #pragma unroll
            for (int k = 0; k < 4; ++k) { ra[k] *= a; rb[k] *= a; }
        }
        // ---- phase B: apply weights, 4 subtiles of 64 rows ----
        for (int sub = 0; sub < 4; ++sub) {
            __syncthreads();
            #pragma unroll
            for (int s = 0; s < 8; ++s) {
                int q = t + 256 * s;
                int rr = q >> 5, cc = q & 31;
                *(float4*)&tileS[rr][cc * 4] =
                    *(const float4*)&in2d[((size_t)i * NRES + j0 + sub * 64 + rr) * C2 + cc * 4];
            }
            __syncthreads();
            if (isR2) {
                for (int jj = 0; jj < 64; jj += 4) {
                    int jt = sub * 64 + jj;
                    float4 p0 = *(const float4*)&P[h0][jt];
                    float4 p1 = *(const float4*)&P[h1][jt];
                    float w0[4] = {p0.x, p0.y, p0.z, p0.w};
                    float w1[4] = {p1.x, p1.y, p1.z, p1.w};
                    #pragma unroll
                    for (int k = 0; k < 4; ++k) {
                        float4 v4 = *(const float4*)&tileS[jj + k][c4 * 4];
                        ra[0] = fmaf(w0[k], v4.x, ra[0]); ra[1] = fmaf(w0[k], v4.y, ra[1]);
                        ra[2] = fmaf(w0[k], v4.z, ra[2]); ra[3] = fmaf(w0[k], v4.w, ra[3]);
                        rb[0] = fmaf(w1[k], v4.x, rb[0]); rb[1] = fmaf(w1[k], v4.y, rb[1]);
                        rb[2] = fmaf(w1[k], v4.z, rb[2]); rb[3] = fmaf(w1[k], v4.w, rb[3]);
                    }
                }
            } else if (vact) {
                for (int jj = 0; jj < 64; jj += 4) {
                    int jt = sub * 64 + jj;
                    int jg = j0 + jt;
                    float4 p = *(const float4*)&P[vh][jt];
                    float w[4] = {p.x, p.y, p.z, p.w};
                    #pragma unroll
                    for (int k = 0; k < 4; ++k) {
                        float4 va = *(const float4*)&vbase[(size_t)(jg + k) * vstride];
                        float4 vb = *(const float4*)&vbase[(size_t)(jg + k) * vstride + 4];
                        ra[0] = fmaf(w[k], va.x, ra[0]); ra[1] = fmaf(w[k], va.y, ra[1]);
                        ra[2] = fmaf(w[k], va.z, ra[2]); ra[3] = fmaf(w[k], va.w, ra[3]);
                        rb[0] = fmaf(w[k], vb.x, rb[0]); rb[1] = fmaf(w[k], vb.y, rb[1]);
                        rb[2] = fmaf(w[k], vb.z, rb[2]); rb[3] = fmaf(w[k], vb.w, rb[3]);
                    }
                }
            }
        }
    }
    // ---- finalize ----
    float* fa = ws + OFF_FA + (size_t)i * 2112;
    if (isR2) {
        float n0v = 1.f / lS[h0], n1v = 1.f / lS[h1];
        *(float4*)&fa[576 + h0 * 128 + c4 * 4] = make_float4(ra[0] * n0v, ra[1] * n0v, ra[2] * n0v, ra[3] * n0v);
        *(float4*)&fa[576 + h1 * 128 + c4 * 4] = make_float4(rb[0] * n1v, rb[1] * n1v, rb[2] * n1v, rb[3] * n1v);
    } else if (vact) {
        float nv = 1.f / lS[vh];
        if (o0 < 192) {
            *(float4*)&fa[o0]     = make_float4(ra[0] * nv, ra[1] * nv, ra[2] * nv, ra[3] * nv);
            *(float4*)&fa[o0 + 4] = make_float4(rb[0] * nv, rb[1] * nv, rb[2] * nv, rb[3] * nv);
        } else {
            int q0 = o0 - 192;
            *(float4*)&rpgS[q0]     = make_float4(ra[0] * nv, ra[1] * nv, ra[2] * nv, ra[3] * nv);
            *(float4*)&rpgS[q0 + 4] = make_float4(rb[0] * nv, rb[1] * nv, rb[2] * nv, rb[3] * nv);
        }
    }
    __syncthreads();
    if (t < 96) {
        int h = t >> 3, p = t & 7;
        float rv[3];
        #pragma unroll
        for (int c = 0; c < 3; ++c) rv[c] = rpgS[h * 24 + p * 3 + c] - trans[i * 3 + c];
        float l0 = rot[i * 9 + 0] * rv[0] + rot[i * 9 + 3] * rv[1] + rot[i * 9 + 6] * rv[2];
        float l1 = rot[i * 9 + 1] * rv[0] + rot[i * 9 + 4] * rv[1] + rot[i * 9 + 7] * rv[2];
        float l2 = rot[i * 9 + 2] * rv[0] + rot[i * 9 + 5] * rv[1] + rot[i * 9 + 8] * rv[2];
        float dd = sqrtf(1e-8f + l0 * l0 + l1 * l1 + l2 * l2);
        fa[192 + t] = l0;
        fa[288 + t] = l1;
        fa[384 + t] = l2;
        fa[480 + t] = dd;
    }
}

// ---------------------------------------------------------------------------
// K3: out = final_act @ w_out.T + b_out.  32x32 tiles, 2x2 micro-tile.
// ---------------------------------------------------------------------------
__global__ __launch_bounds__(256) void k3_out(
    const float* __restrict__ w_out, const float* __restrict__ b_out,
    const float* __restrict__ ws, float* __restrict__ out)
{
    __shared__ __align__(16) float ASt[32][34];
    __shared__ __align__(16) float WSt[32][34];
    const int t = threadIdx.x;
    const int i0 = blockIdx.x * 32;
    const int o0 = blockIdx.y * 32;
    const float* fa = ws + OFF_FA;
    int tx = t & 15, ty = t >> 4;
    float acc00 = 0.f, acc01 = 0.f, acc10 = 0.f, acc11 = 0.f;
    int r = t >> 3, kq = (t & 7) * 4;

    for (int k0 = 0; k0 < 2112; k0 += 32) {
        __syncthreads();
        {
            float4 a4 = *(const float4*)&fa[(size_t)(i0 + r) * 2112 + k0 + kq];
            ASt[kq + 0][r] = a4.x; ASt[kq + 1][r] = a4.y; ASt[kq + 2][r] = a4.z; ASt[kq + 3][r] = a4.w;
            float4 w4 = *(const float4*)&w_out[(size_t)(o0 + r) * 2112 + k0 + kq];
            WSt[kq + 0][r] = w4.x; WSt[kq + 1][r] = w4.y; WSt[kq + 2][r] = w4.z; WSt[kq + 3][r] = w4.w;
        }
        __syncthreads();
        #pragma unroll
        for (int k = 0; k < 32; ++k) {
            float2 av = *(const float2*)&ASt[k][ty * 2];
            float2 wv = *(const float2*)&WSt[k][tx * 2];
            acc00 = fmaf(av.x, wv.x, acc00);
            acc01 = fmaf(av.x, wv.y, acc01);
            acc10 = fmaf(av.y, wv.x, acc10);
            acc11 = fmaf(av.y, wv.y, acc11);
        }
    }
    int oi = i0 + ty * 2, oo = o0 + tx * 2;
    out[(size_t)oi * 384 + oo]           = acc00 + b_out[oo];
    out[(size_t)oi * 384 + oo + 1]       = acc01 + b_out[oo + 1];
    out[(size_t)(oi + 1) * 384 + oo]     = acc10 + b_out[oo];
    out[(size_t)(oi + 1) * 384 + oo + 1] = acc11 + b_out[oo + 1];
}

extern "C" void kernel_launch(void* const* d_in, const int* in_sizes, int n_in,
                              void* d_out, int out_size, void* d_ws, size_t ws_size,
                              hipStream_t stream) {
    const float* in1d  = (const float*)d_in[0];
    const float* in2d  = (const float*)d_in[1];
    const float* mask  = (const float*)d_in[2];
    const float* rot   = (const float*)d_in[3];
    const float* trans = (const float*)d_in[4];
    const float* w_qs  = (const float*)d_in[5];
    const float* b_qs  = (const float*)d_in[6];
    const float* w_kvs = (const float*)d_in[7];
    const float* b_kvs = (const float*)d_in[8];
    const float* w_qp  = (const float*)d_in[9];
    const float* b_qp  = (const float*)d_in[10];
    const float* w_kvp = (const float*)d_in[11];
    const float* b_kvp = (const float*)d_in[12];
    const float* tpw   = (const float*)d_in[13];
    const float* w2d   = (const float*)d_in[14];
    const float* b2d   = (const float*)d_in[15];
    const float* w_out = (const float*)d_in[16];
    const float* b_out = (const float*)d_in[17];
    float* ws  = (float*)d_ws;
    float* out = (float*)d_out;

    hipLaunchKernelGGL(k1_gemm, dim3(12, 18), dim3(256), 0, stream,
                       in1d, w_qs, b_qs, w_kvs, b_kvs, w_qp, b_qp, w_kvp, b_kvp, ws);
    hipLaunchKernelGGL(k1b_scatter, dim3(768), dim3(256), 0, stream,
                       rot, trans, ws);
    hipLaunchKernelGGL(k2_attn, dim3(768), dim3(256), 0, stream,
                       in2d, mask, rot, trans, tpw, w2d, b2d, ws);
    hipLaunchKernelGGL(k3_out, dim3(24, 12), dim3(256), 0, stream,
                       w_out, b_out, ws, out);
}